// Round 3
// baseline (224.065 us; speedup 1.0000x reference)
//
#include <hip/hip_runtime.h>

// GraphConvolution: out[b,n,o] = sum_m adj[n,m] * (F[b,m,:] . W[o,:]) + b[o]
// B=8192, N=4, DIN=1024, DOUT=256. G = F_bf16 @ W_bf16^T via MFMA 16x16x32,
// adj 4x4 mix on fp32 accumulators in the epilogue (C/D row=(lane>>4)*4+reg
// -> the 4 rows of one batch live in one lane's 4 acc regs).
// R3: B never touches LDS. wprep writes W as [k8][col][8 bf16] = exact MFMA
// B-fragment order, so gconv loads B frags straight global->VGPR (L2-resident,
// coalesced 256B runs). K-loop: A-only double-buffered LDS, ONE barrier/iter,
// no global_load_lds queue to drain at the barrier.

#define DIN 1024
#define DOUT 256
#define BM 64
#define BK 64
#define KI 16                      // DIN / BK
#define LDA 72                     // A row stride in bf16 (16B multiple)
#define A_HALFS (BM * LDA)         // 4608 per buffer

typedef __bf16 bf16x8 __attribute__((ext_vector_type(8)));
typedef float f32x4 __attribute__((ext_vector_type(4)));
typedef unsigned short u16x8 __attribute__((ext_vector_type(8)));

__device__ __forceinline__ unsigned short f2bf(float f) {
  union { float f; unsigned int u; } v;
  v.f = f;
  unsigned int u = v.u;
  u += 0x7fffu + ((u >> 16) & 1u);   // round-to-nearest-even
  return (unsigned short)(u >> 16);
}

// wprep: W [256x1024] fp32 -> ws [k8=128][col=256][8] bf16 (B-fragment order).
__global__ __launch_bounds__(256) void wprep_kernel(
    const float* __restrict__ W, unsigned short* __restrict__ ws) {
  const int t = blockIdx.x * 256 + threadIdx.x;  // 32768 threads
  const int k8 = t >> 8;                         // 0..127
  const int col = t & 255;
  const f32x4* src = (const f32x4*)(W + (size_t)col * DIN + k8 * 8);
  f32x4 a = src[0], b = src[1];
  u16x8 pk;
#pragma unroll
  for (int m = 0; m < 4; ++m) {
    pk[m] = f2bf(a[m]);
    pk[4 + m] = f2bf(b[m]);
  }
  *(u16x8*)(ws + ((size_t)k8 * 256 + col) * 8) = pk;  // coalesced 4KB runs
}

__global__ __launch_bounds__(256, 2) void gconv_kernel(
    const float* __restrict__ adj, const float* __restrict__ feat,
    const unsigned short* __restrict__ wbf, const float* __restrict__ bias,
    float* __restrict__ out) {
  __shared__ __align__(16) unsigned short sA[2][A_HALFS];  // A double buffer

  const int tid = threadIdx.x;
  const int bM = blockIdx.x * BM;

  // A staging: thread owns 32-B chunks tid and tid+256 of the 64x64 tile
  const int row0 = tid >> 3;          // 0..31
  const int kc0 = (tid & 7) * 8;
  const int row1 = row0 + 32;
  const float* aptr0 = feat + (size_t)(bM + row0) * DIN + kc0;
  const float* aptr1 = feat + (size_t)(bM + row1) * DIN + kc0;
  const int sw0 = row0 * LDA + kc0;
  const int sw1 = row1 * LDA + kc0;

  // wave coords: 1x4 wave grid, 64 rows x 64 cols per wave
  const int lane = tid & 63;
  const int wid = tid >> 6;
  const int wc = wid * 64;
  const int rl = lane & 15;
  const int q = lane >> 4;

  f32x4 acc[4][4];
#pragma unroll
  for (int i = 0; i < 4; ++i)
#pragma unroll
    for (int j = 0; j < 4; ++j) acc[i][j] = f32x4{0.f, 0.f, 0.f, 0.f};

  // prologue: A(0) -> regs -> sA[0]; A(1) -> regs
  f32x4 pa0 = *(const f32x4*)aptr0;
  f32x4 pa1 = *(const f32x4*)(aptr0 + 4);
  f32x4 pa2 = *(const f32x4*)aptr1;
  f32x4 pa3 = *(const f32x4*)(aptr1 + 4);
  aptr0 += BK; aptr1 += BK;
  {
    u16x8 pk0, pk1;
#pragma unroll
    for (int m = 0; m < 4; ++m) {
      pk0[m] = f2bf(pa0[m]); pk0[4 + m] = f2bf(pa1[m]);
      pk1[m] = f2bf(pa2[m]); pk1[4 + m] = f2bf(pa3[m]);
    }
    *(u16x8*)(sA[0] + sw0) = pk0;
    *(u16x8*)(sA[0] + sw1) = pk1;
  }
  pa0 = *(const f32x4*)aptr0;
  pa1 = *(const f32x4*)(aptr0 + 4);
  pa2 = *(const f32x4*)aptr1;
  pa3 = *(const f32x4*)(aptr1 + 4);
  aptr0 += BK; aptr1 += BK;
  __syncthreads();

  // B-fragment base for this lane: ws[(k8)*256 + col]*8, col = wc + j*16 + rl
  const unsigned short* bbase = wbf + ((size_t)wc + rl) * 8 + (size_t)q * 256 * 8;

  for (int kb = 0; kb < KI; ++kb) {
    const int p = kb & 1;

    // B(kb) frags straight from global (L2-hot, exact fragment layout)
    bf16x8 bfr[2][4];
#pragma unroll
    for (int ks = 0; ks < 2; ++ks)
#pragma unroll
      for (int j = 0; j < 4; ++j)
        bfr[ks][j] = *(const bf16x8*)(bbase +
            ((size_t)(kb * 8 + ks * 4) * 256 + j * 16) * 8);

    // convert A(kb+1) regs -> sA[p^1]
    if (kb + 1 < KI) {
      u16x8 pk0, pk1;
#pragma unroll
      for (int m = 0; m < 4; ++m) {
        pk0[m] = f2bf(pa0[m]); pk0[4 + m] = f2bf(pa1[m]);
        pk1[m] = f2bf(pa2[m]); pk1[4 + m] = f2bf(pa3[m]);
      }
      *(u16x8*)(sA[p ^ 1] + sw0) = pk0;
      *(u16x8*)(sA[p ^ 1] + sw1) = pk1;
      // prefetch A(kb+2)
      if (kb + 2 < KI) {
        pa0 = *(const f32x4*)aptr0;
        pa1 = *(const f32x4*)(aptr0 + 4);
        pa2 = *(const f32x4*)aptr1;
        pa3 = *(const f32x4*)(aptr1 + 4);
        aptr0 += BK; aptr1 += BK;
      }
    }

    // A(kb) frags from sA[p], MFMA
#pragma unroll
    for (int ks = 0; ks < 2; ++ks) {
      const int ko = ks * 32 + q * 8;
      bf16x8 af[4];
#pragma unroll
      for (int i = 0; i < 4; ++i)
        af[i] = *(const bf16x8*)(sA[p] + (i * 16 + rl) * LDA + ko);
#pragma unroll
      for (int i = 0; i < 4; ++i)
#pragma unroll
        for (int j = 0; j < 4; ++j)
          acc[i][j] = __builtin_amdgcn_mfma_f32_16x16x32_bf16(
              af[i], bfr[ks][j], acc[i][j], 0, 0, 0);
    }
    __syncthreads();
  }

  // epilogue: adj 4x4 mix (intra-lane: regs = rows 4q..4q+3) + bias
  float am[16];
#pragma unroll
  for (int i = 0; i < 16; ++i) am[i] = adj[i];  // uniform -> scalar loads

  float bv[4];
#pragma unroll
  for (int j = 0; j < 4; ++j) bv[j] = bias[wc + j * 16 + rl];

#pragma unroll
  for (int i = 0; i < 4; ++i) {
    const size_t rowbase = (size_t)(bM + i * 16 + q * 4);
#pragma unroll
    for (int j = 0; j < 4; ++j) {
      const int col = wc + j * 16 + rl;
      float* op = out + rowbase * DOUT + col;
      f32x4 g = acc[i][j];
#pragma unroll
      for (int n = 0; n < 4; ++n) {
        op[(size_t)n * DOUT] = am[n * 4 + 0] * g[0] + am[n * 4 + 1] * g[1] +
                               am[n * 4 + 2] * g[2] + am[n * 4 + 3] * g[3] +
                               bv[j];
      }
    }
  }
}

extern "C" void kernel_launch(void* const* d_in, const int* in_sizes, int n_in,
                              void* d_out, int out_size, void* d_ws,
                              size_t ws_size, hipStream_t stream) {
  const float* adj = (const float*)d_in[0];
  const float* feat = (const float*)d_in[1];
  const float* W = (const float*)d_in[2];
  const float* bias = (const float*)d_in[3];
  float* out = (float*)d_out;
  unsigned short* ws = (unsigned short*)d_ws;  // 512 KiB used

  wprep_kernel<<<128, 256, 0, stream>>>(W, ws);
  gconv_kernel<<<8192 * 4 / BM, 256, 0, stream>>>(adj, feat, ws, bias, out);
}